// Round 1
// baseline (212.837 us; speedup 1.0000x reference)
//
#include <hip/hip_runtime.h>
#include <hip/hip_bf16.h>
#include <stdint.h>

// ---------------------------------------------------------------------------
// TensorDense (tensor-train layer):
//   out[n, abc] = relu( sum_{xyz} x[n, xyz] * W[xyz, abc] + bias[abc] )
//   W[xyz, abc] = sum_{p,q} c1[x,a,p] c2[y,b,p,q] c3[z,c,q]
//
// Plan: materialize Wt = W^T (bf16, [j=abc][k=xyz]) from the TT cores
// (~1.2 GFLOP), then one bf16 MFMA GEMM (68.7 GFLOP) with fused bias+relu.
// ---------------------------------------------------------------------------

typedef short bf16x8 __attribute__((ext_vector_type(8)));  // 8 bf16 = 4 VGPR
typedef float f32x4  __attribute__((ext_vector_type(4)));

#define MB 2048      // batch
#define KD 4096      // input features  (x*256 + y*16 + z)
#define ND 4096      // output features (a*256 + b*16 + c)

__device__ __forceinline__ unsigned short f32_bf16(float f) {
  union { float f; uint32_t u; } v; v.f = f;
  return (unsigned short)((v.u + 0x7fffu + ((v.u >> 16) & 1u)) >> 16);  // RNE
}

// --- K0a: x fp32 -> bf16 (8 elems/thread, float4 in / ushort4 out) ---------
__global__ void k_conv_x(const float* __restrict__ x, unsigned short* __restrict__ xb) {
  int i = blockIdx.x * 256 + threadIdx.x;
  const float4* x4 = (const float4*)x;
  float4 a = x4[2*i];
  float4 b = x4[2*i+1];
  ushort4 lo, hi;
  lo.x = f32_bf16(a.x); lo.y = f32_bf16(a.y); lo.z = f32_bf16(a.z); lo.w = f32_bf16(a.w);
  hi.x = f32_bf16(b.x); hi.y = f32_bf16(b.y); hi.z = f32_bf16(b.z); hi.w = f32_bf16(b.w);
  ushort4* o = (ushort4*)xb;
  o[2*i]   = lo;
  o[2*i+1] = hi;
}

// --- K0b: c3[z][c][q] -> c3p[(c*16+z)][q]  bf16 ----------------------------
// (c,z) packing puts z on the MFMA N-dim fast axis so stage-B stores are
// 16-lane x 2B = 32B contiguous chunks in Wt.
__global__ void k_pack_c3(const float* __restrict__ c3, unsigned short* __restrict__ c3p) {
  int idx = blockIdx.x * 256 + threadIdx.x;   // 8192 total
  int q = idx & 31, cz = idx >> 5;
  int c = cz >> 4, z = cz & 15;
  c3p[idx] = f32_bf16(c3[(z*16 + c)*32 + q]);
}

// --- K1: T2[(a*16+b)][(x*16+y)][q] = sum_p c1[x][a][p] * c2[y][b][p][q] ----
__global__ __launch_bounds__(256) void k_stageA(const float* __restrict__ c1,
                                                const float* __restrict__ c2,
                                                unsigned short* __restrict__ T2) {
  int ab = blockIdx.x;          // 256 blocks
  int xy = threadIdx.x;         // 256 threads
  int a = ab >> 4, b = ab & 15;
  int x = xy >> 4, y = xy & 15;
  const float* c1r = c1 + (x*16 + a)*32;      // [p], contiguous
  const float* c2r = c2 + (y*16 + b)*1024;    // [p][q], q contiguous
  float acc[32];
  #pragma unroll
  for (int q = 0; q < 32; ++q) acc[q] = 0.f;
  #pragma unroll 8
  for (int p = 0; p < 32; ++p) {
    float w = c1r[p];
    const float4* row = (const float4*)(c2r + p*32);
    #pragma unroll
    for (int j = 0; j < 8; ++j) {
      float4 v = row[j];
      acc[4*j+0] = fmaf(w, v.x, acc[4*j+0]);
      acc[4*j+1] = fmaf(w, v.y, acc[4*j+1]);
      acc[4*j+2] = fmaf(w, v.z, acc[4*j+2]);
      acc[4*j+3] = fmaf(w, v.w, acc[4*j+3]);
    }
  }
  ushort4* o = (ushort4*)(T2 + ((size_t)ab*256 + xy)*32);   // 64B contiguous
  #pragma unroll
  for (int j = 0; j < 8; ++j) {
    ushort4 v;
    v.x = f32_bf16(acc[4*j+0]); v.y = f32_bf16(acc[4*j+1]);
    v.z = f32_bf16(acc[4*j+2]); v.w = f32_bf16(acc[4*j+3]);
    o[j] = v;
  }
}

// --- K2: batched MFMA  D[xy][cz] = sum_q T2[ab][xy][q] * c3p[cz][q] --------
// One 16x16x32 MFMA per output tile (K = bond = 32 exactly).
// D lane layout (verified m89/m91): row = (l>>4)*4 + reg, col = l&15.
// Store: Wt[(ab*16 + c)*4096 + xy*16 + z], c = ntile, z = l&15.
__global__ __launch_bounds__(256) void k_stageB(const unsigned short* __restrict__ T2,
                                                const unsigned short* __restrict__ c3p,
                                                unsigned short* __restrict__ Wt) {
  int ab = blockIdx.x >> 1;     // 512 blocks = 256 ab * 2 halves
  int h  = blockIdx.x & 1;
  int wid = threadIdx.x >> 6, lane = threadIdx.x & 63;
  int l15 = lane & 15, lg = lane >> 4;
  bf16x8 bf[16];                // all 16 B-fragments (k-contiguous loads)
  #pragma unroll
  for (int nt = 0; nt < 16; ++nt)
    bf[nt] = *(const bf16x8*)(c3p + (nt*16 + l15)*32 + lg*8);
  const unsigned short* Tab = T2 + (size_t)ab*8192;
  #pragma unroll
  for (int mi = 0; mi < 2; ++mi) {
    int mtile = h*8 + wid*2 + mi;
    bf16x8 af = *(const bf16x8*)(Tab + (mtile*16 + l15)*32 + lg*8);
    #pragma unroll
    for (int nt = 0; nt < 16; ++nt) {
      f32x4 d = {0.f, 0.f, 0.f, 0.f};
      d = __builtin_amdgcn_mfma_f32_16x16x32_bf16(af, bf[nt], d, 0, 0, 0);
      size_t jrow = (size_t)(ab*16 + nt) * 4096;
      #pragma unroll
      for (int i = 0; i < 4; ++i) {
        int xy = mtile*16 + lg*4 + i;
        Wt[jrow + xy*16 + l15] = f32_bf16(d[i]);
      }
    }
  }
}

// --- K3: GEMM out[n][j] = relu(sum_k xb[n][k]*Wt[j][k] + bias[j]) ----------
// m97 structure: 128x128 tile, BK=32, 4 waves (2x2), 4x4 fragments/wave,
// global_load_lds width 16 (linear LDS), 2 barriers per K-step.
__device__ __forceinline__ void gload_lds16(const unsigned short* g, unsigned short* l) {
  __builtin_amdgcn_global_load_lds(
      (const __attribute__((address_space(1))) void*)g,
      (__attribute__((address_space(3))) void*)l, 16, 0, 0);
}

__global__ __launch_bounds__(256, 2) void k_gemm(const unsigned short* __restrict__ A,
                                                 const unsigned short* __restrict__ Bw,
                                                 const float* __restrict__ bias,
                                                 float* __restrict__ C) {
  __shared__ unsigned short As[128*32];   // 8 KB
  __shared__ unsigned short Bs[128*32];   // 8 KB
  int tid = threadIdx.x;
  int wid = tid >> 6, lane = tid & 63;
  int l15 = lane & 15, lg = lane >> 4;
  int m0 = blockIdx.y * 128;              // batch rows
  int n0 = blockIdx.x * 128;              // output cols
  int wr = wid >> 1, wc = wid & 1;        // wave grid 2x2 over 128x128

  // staging: per load inst a wave writes 1KB linear LDS (lane*16B);
  // global src = matching [row][k] position (both A and Wt are k-contiguous)
  int srow  = wid*16 + (lane >> 2);       // + s*64
  int scol  = (lane & 3)*8;
  int lflat = wid*512 + lane*8;           // + s*2048 ; == row*32 + col

  const unsigned short* Ag = A  + (size_t)(m0 + srow)*KD + scol;
  const unsigned short* Bg = Bw + (size_t)(n0 + srow)*KD + scol;

  f32x4 acc[4][4];
  #pragma unroll
  for (int m = 0; m < 4; ++m)
    #pragma unroll
    for (int n = 0; n < 4; ++n)
      acc[m][n] = (f32x4){0.f, 0.f, 0.f, 0.f};

  for (int kt = 0; kt < KD/32; ++kt) {
    int kb = kt*32;
    gload_lds16(Ag + kb,          As + lflat);
    gload_lds16(Ag + 64*KD + kb,  As + 2048 + lflat);
    gload_lds16(Bg + kb,          Bs + lflat);
    gload_lds16(Bg + 64*KD + kb,  Bs + 2048 + lflat);
    __syncthreads();   // compiler emits vmcnt(0) drain before s_barrier
    bf16x8 aF[4], bF[4];
    #pragma unroll
    for (int m = 0; m < 4; ++m)
      aF[m] = *(const bf16x8*)(As + (wr*64 + m*16 + l15)*32 + lg*8);
    #pragma unroll
    for (int n = 0; n < 4; ++n)
      bF[n] = *(const bf16x8*)(Bs + (wc*64 + n*16 + l15)*32 + lg*8);
    #pragma unroll
    for (int m = 0; m < 4; ++m)
      #pragma unroll
      for (int n = 0; n < 4; ++n)
        acc[m][n] = __builtin_amdgcn_mfma_f32_16x16x32_bf16(aF[m], bF[n], acc[m][n], 0, 0, 0);
    __syncthreads();
  }

  // epilogue: bias + relu, fp32 stores (16-lane x 4B = 64B chunks)
  #pragma unroll
  for (int m = 0; m < 4; ++m) {
    int gr = m0 + wr*64 + m*16 + lg*4;
    #pragma unroll
    for (int n = 0; n < 4; ++n) {
      int gc = n0 + wc*64 + n*16 + l15;
      float bv = bias[gc];
      #pragma unroll
      for (int i = 0; i < 4; ++i) {
        float v = acc[m][n][i] + bv;
        C[(size_t)(gr + i)*ND + gc] = v > 0.f ? v : 0.f;
      }
    }
  }
}

// ---------------------------------------------------------------------------
extern "C" void kernel_launch(void* const* d_in, const int* in_sizes, int n_in,
                              void* d_out, int out_size, void* d_ws, size_t ws_size,
                              hipStream_t stream) {
  (void)in_sizes; (void)n_in; (void)out_size; (void)ws_size;
  const float* x    = (const float*)d_in[0];   // [2048][4096]
  const float* c1   = (const float*)d_in[1];   // [16][16][32]
  const float* c2   = (const float*)d_in[2];   // [16][16][32][32]
  const float* c3   = (const float*)d_in[3];   // [16][16][32]
  const float* bias = (const float*)d_in[4];   // [4096]
  float* out = (float*)d_out;                  // [2048][4096]

  uint8_t* ws = (uint8_t*)d_ws;
  unsigned short* xb  = (unsigned short*)(ws);                        // 16 MB
  unsigned short* T2  = (unsigned short*)(ws + 16777216);             //  4 MB
  unsigned short* c3p = (unsigned short*)(ws + 16777216 + 4194304);   // 16 KB
  unsigned short* Wt  = (unsigned short*)(ws + 16777216 + 4194304 + 16384); // 32 MB

  k_conv_x <<<4096, 256, 0, stream>>>(x, xb);
  k_pack_c3<<<32,   256, 0, stream>>>(c3, c3p);
  k_stageA <<<256,  256, 0, stream>>>(c1, c2, T2);
  k_stageB <<<512,  256, 0, stream>>>(T2, c3p, Wt);
  k_gemm   <<<dim3(ND/128, MB/128), 256, 0, stream>>>(xb, Wt, bias, out);
}

// Round 5
// 177.819 us; speedup vs baseline: 1.1969x; 1.1969x over previous
//
#include <hip/hip_runtime.h>
#include <hip/hip_bf16.h>
#include <stdint.h>

// ---------------------------------------------------------------------------
// TensorDense (tensor-train layer):
//   out[n, abc] = relu( sum_{xyz} x[n, xyz] * W[xyz, abc] + bias[abc] )
//   W[xyz, abc] = sum_{p,q} c1[x,a,p] c2[y,b,p,q] c3[z,c,q]
//
// 2 dispatches:
//   k_prep : blocks [0,4096) convert x fp32->bf16 (BW-bound);
//            blocks [4096,4352) build Wt^T rows for one (a,b) each.
//   k_gemm : 128x128 tile, BK=64, 4 waves, global_load_lds w16 (linear dest,
//            pre-swizzled source), XOR-swizzled ds_read_b128 (rule 21:
//            SAME involution on full 3-bit col16 index on BOTH sides),
//            fused bias+relu epilogue.
// ---------------------------------------------------------------------------

typedef short bf16x8 __attribute__((ext_vector_type(8)));  // 8 bf16 = 4 VGPR
typedef float f32x4  __attribute__((ext_vector_type(4)));

#define MB 2048      // batch
#define KD 4096      // input features  (x*256 + y*16 + z)
#define ND 4096      // output features (a*256 + b*16 + c)

__device__ __forceinline__ unsigned short f32_bf16(float f) {
  union { float f; uint32_t u; } v; v.f = f;
  return (unsigned short)((v.u + 0x7fffu + ((v.u >> 16) & 1u)) >> 16);  // RNE
}
__device__ __forceinline__ float bf2f(unsigned short u) {
  union { uint32_t i; float f; } v; v.i = ((uint32_t)u) << 16; return v.f;
}

// ---------------------------------------------------------------------------
// K0: fused prep.  LDS layout (union, 34944 B):
//   phase A: c2s = sh[0 .. 16448) shorts (16 rows x 1028, +4 pad for banks)
//            c1s = float[512] at sh+16448 shorts (2 KB)
//   phase B: T2s  = sh[0 .. 8192)   shorts  (aliases dead c2s)
//            c3ps = sh[8192..16384) shorts
__global__ __launch_bounds__(256) void k_prep(const float* __restrict__ x,
                                              const float* __restrict__ c1,
                                              const float* __restrict__ c2,
                                              const float* __restrict__ c3,
                                              unsigned short* __restrict__ xb,
                                              unsigned short* __restrict__ Wt) {
  __shared__ unsigned short sh[17472];   // 34944 B
  int bid = blockIdx.x;
  int t = threadIdx.x;

  if (bid < 4096) {            // ---- x fp32 -> bf16, 8 elems/thread ----
    int i = bid * 256 + t;
    const float4* x4 = (const float4*)x;
    float4 a = x4[2*i];
    float4 b = x4[2*i+1];
    ushort4 lo, hi;
    lo.x = f32_bf16(a.x); lo.y = f32_bf16(a.y); lo.z = f32_bf16(a.z); lo.w = f32_bf16(a.w);
    hi.x = f32_bf16(b.x); hi.y = f32_bf16(b.y); hi.z = f32_bf16(b.z); hi.w = f32_bf16(b.w);
    ushort4* o = (ushort4*)xb;
    o[2*i]   = lo;
    o[2*i+1] = hi;
    return;
  }

  // ---- weights block: one (a,b) pair ----
  int ab = bid - 4096;
  int a = ab >> 4, b = ab & 15;
  unsigned short* c2s = sh;                       // [16][1028] shorts
  float* c1s = (float*)(sh + 16448);              // [16][32]

  // stage c2 rows (y,b) -> bf16 LDS, coalesced (4 KB per y-row)
  #pragma unroll
  for (int y = 0; y < 16; ++y) {
    float4 v = *(const float4*)(c2 + (size_t)(y*16 + b)*1024 + t*4);
    ushort4 s;
    s.x = f32_bf16(v.x); s.y = f32_bf16(v.y); s.z = f32_bf16(v.z); s.w = f32_bf16(v.w);
    *(ushort4*)(c2s + y*1028 + t*4) = s;
  }
  // stage c1 rows (x,a) fp32 (512 floats)
  c1s[t]       = c1[((t>>5)*16 + a)*32 + (t&31)];
  c1s[t+256]   = c1[(((t>>5)+8)*16 + a)*32 + (t&31)];
  __syncthreads();

  // phase A: T2[xy][q] = sum_p c1[x][p] * c2[y][p][q]   (acc in regs)
  int xx = t >> 4, yy = t & 15;
  const float* c1r = c1s + xx*32;                 // broadcast within 16 lanes
  const unsigned short* c2r = c2s + yy*1028;      // 2-elem bank stride: free
  float acc[32];
  #pragma unroll
  for (int q = 0; q < 32; ++q) acc[q] = 0.f;
  #pragma unroll 8
  for (int p = 0; p < 32; ++p) {
    float w = c1r[p];
    #pragma unroll
    for (int j = 0; j < 8; ++j) {
      ushort4 v = *(const ushort4*)(c2r + p*32 + j*4);
      acc[4*j+0] = fmaf(w, bf2f(v.x), acc[4*j+0]);
      acc[4*j+1] = fmaf(w, bf2f(v.y), acc[4*j+1]);
      acc[4*j+2] = fmaf(w, bf2f(v.z), acc[4*j+2]);
      acc[4*j+3] = fmaf(w, bf2f(v.w), acc[4*j+3]);
    }
  }
  __syncthreads();   // all c2s reads done; region is reusable now

  unsigned short* T2s  = sh;          // [256][32] shorts
  unsigned short* c3ps = sh + 8192;   // [256][32] shorts

  // write T2 row (this thread's xy) as bf16
  #pragma unroll
  for (int j = 0; j < 8; ++j) {
    ushort4 s;
    s.x = f32_bf16(acc[4*j+0]); s.y = f32_bf16(acc[4*j+1]);
    s.z = f32_bf16(acc[4*j+2]); s.w = f32_bf16(acc[4*j+3]);
    *(ushort4*)(T2s + t*32 + j*4) = s;
  }
  // stage c3 -> c3ps[(c*16+z)][q] bf16 (permuted)
  #pragma unroll
  for (int r = 0; r < 8; ++r) {
    int i4 = t*8 + r;                          // float4 index into c3
    float4 v = *(const float4*)(c3 + (size_t)i4*4);
    int e = i4*4;
    int q = e & 31, zc = e >> 5;
    int z = zc >> 4, c = zc & 15;
    ushort4 s;
    s.x = f32_bf16(v.x); s.y = f32_bf16(v.y); s.z = f32_bf16(v.z); s.w = f32_bf16(v.w);
    *(ushort4*)(c3ps + (c*16 + z)*32 + q) = s;
  }
  __syncthreads();

  // phase B: Wt rows via MFMA.  D row=(l>>4)*4+reg, col=l&15 (m89/m91).
  int wid = t >> 6, lane = t & 63, l15 = lane & 15, lg = lane >> 4;
  bf16x8 bfv[16];
  #pragma unroll
  for (int nt = 0; nt < 16; ++nt)
    bfv[nt] = *(const bf16x8*)(c3ps + (nt*16 + l15)*32 + lg*8);
  #pragma unroll
  for (int mi = 0; mi < 4; ++mi) {
    int mtile = wid*4 + mi;
    bf16x8 af = *(const bf16x8*)(T2s + (mtile*16 + l15)*32 + lg*8);
    #pragma unroll
    for (int nt = 0; nt < 16; ++nt) {
      f32x4 d = {0.f, 0.f, 0.f, 0.f};
      d = __builtin_amdgcn_mfma_f32_16x16x32_bf16(af, bfv[nt], d, 0, 0, 0);
      size_t jrow = (size_t)(ab*16 + nt) * ND;
      #pragma unroll
      for (int i = 0; i < 4; ++i) {
        int xy = mtile*16 + lg*4 + i;
        Wt[jrow + xy*16 + l15] = f32_bf16(d[i]);
      }
    }
  }
}

// ---------------------------------------------------------------------------
// K1: GEMM out[n][j] = relu(sum_k xb[n][k]*Wt[j][k] + bias[j])
// 128x128 tile, BK=64, 4 waves (2x2), 2x(4x4) MFMA per K-step.
// LDS [128][64] shorts per matrix; XOR swizzle on 16B slots:
//   physical_col16 = logical_col16 ^ (row&7)   (full 3-bit involution!)
//   - staging: linear LDS dest, source col16 pre-swizzled (full 3-bit XOR)
//   - reads:   physical col16 = (kk*4+lg) ^ (l15&7)  (full 3-bit XOR —
//              the kk bit participates; R3's bug applied XOR to lg only)
__device__ __forceinline__ void gload_lds16(const unsigned short* g, unsigned short* l) {
  __builtin_amdgcn_global_load_lds(
      (const __attribute__((address_space(1))) void*)g,
      (__attribute__((address_space(3))) void*)l, 16, 0, 0);
}

__global__ __launch_bounds__(256, 2) void k_gemm(const unsigned short* __restrict__ A,
                                                 const unsigned short* __restrict__ Bw,
                                                 const float* __restrict__ bias,
                                                 float* __restrict__ C) {
  __shared__ unsigned short As[128*64];   // 16 KB
  __shared__ unsigned short Bs[128*64];   // 16 KB
  int t = threadIdx.x;
  int wid = t >> 6, lane = t & 63;
  int l15 = lane & 15, lg = lane >> 4;
  int m0 = blockIdx.y * 128;
  int n0 = blockIdx.x * 128;
  int wr = wid >> 1, wc = wid & 1;

  // staging: inst s writes LDS shorts [s*2048 + t*8, +8) == row s*32+(t>>3),
  // physical col16 (t&7). Source col16 = (t&7) ^ (row&7), row&7 == (t>>3)&7.
  int scol = (((t & 7) ^ ((t >> 3) & 7)) * 8);
  int lds_off = t * 8;
  const unsigned short* Ag = A  + (size_t)(m0 + (t >> 3))*KD + scol;
  const unsigned short* Bg = Bw + (size_t)(n0 + (t >> 3))*KD + scol;

  int xr = l15 & 7;   // row&7 for all this lane's fragment rows

  f32x4 acc[4][4];
  #pragma unroll
  for (int m = 0; m < 4; ++m)
    #pragma unroll
    for (int n = 0; n < 4; ++n)
      acc[m][n] = (f32x4){0.f, 0.f, 0.f, 0.f};

  for (int kt = 0; kt < KD/64; ++kt) {
    int kb = kt * 64;
    #pragma unroll
    for (int s = 0; s < 4; ++s) {
      gload_lds16(Ag + kb + (size_t)s*32*KD, As + lds_off + s*2048);
      gload_lds16(Bg + kb + (size_t)s*32*KD, Bs + lds_off + s*2048);
    }
    __syncthreads();
    bf16x8 aF[2][4], bF[2][4];
    #pragma unroll
    for (int kk = 0; kk < 2; ++kk) {
      int pc = ((kk*4 + lg) ^ xr) * 8;   // physical col shorts, full 3-bit XOR
      #pragma unroll
      for (int m = 0; m < 4; ++m)
        aF[kk][m] = *(const bf16x8*)(As + (wr*64 + m*16 + l15)*64 + pc);
      #pragma unroll
      for (int n = 0; n < 4; ++n)
        bF[kk][n] = *(const bf16x8*)(Bs + (wc*64 + n*16 + l15)*64 + pc);
    }
    #pragma unroll
    for (int kk = 0; kk < 2; ++kk)
      #pragma unroll
      for (int m = 0; m < 4; ++m)
        #pragma unroll
        for (int n = 0; n < 4; ++n)
          acc[m][n] = __builtin_amdgcn_mfma_f32_16x16x32_bf16(aF[kk][m], bF[kk][n],
                                                              acc[m][n], 0, 0, 0);
    __syncthreads();
  }

  // epilogue: bias + relu, fp32 stores
  #pragma unroll
  for (int m = 0; m < 4; ++m) {
    int gr = m0 + wr*64 + m*16 + lg*4;
    #pragma unroll
    for (int n = 0; n < 4; ++n) {
      int gc = n0 + wc*64 + n*16 + l15;
      float bv = bias[gc];
      #pragma unroll
      for (int i = 0; i < 4; ++i) {
        float v = acc[m][n][i] + bv;
        C[(size_t)(gr + i)*ND + gc] = v > 0.f ? v : 0.f;
      }
    }
  }
}

// ---------------------------------------------------------------------------
extern "C" void kernel_launch(void* const* d_in, const int* in_sizes, int n_in,
                              void* d_out, int out_size, void* d_ws, size_t ws_size,
                              hipStream_t stream) {
  (void)in_sizes; (void)n_in; (void)out_size; (void)ws_size;
  const float* x    = (const float*)d_in[0];   // [2048][4096]
  const float* c1   = (const float*)d_in[1];   // [16][16][32]
  const float* c2   = (const float*)d_in[2];   // [16][16][32][32]
  const float* c3   = (const float*)d_in[3];   // [16][16][32]
  const float* bias = (const float*)d_in[4];   // [4096]
  float* out = (float*)d_out;                  // [2048][4096]

  uint8_t* ws = (uint8_t*)d_ws;
  unsigned short* xb = (unsigned short*)(ws);              // 16 MB
  unsigned short* Wt = (unsigned short*)(ws + 16777216);   // 32 MB

  k_prep<<<4096 + 256, 256, 0, stream>>>(x, c1, c2, c3, xb, Wt);
  k_gemm<<<dim3(ND/128, MB/128), 256, 0, stream>>>(xb, Wt, bias, out);
}